// Round 1
// baseline (1285.955 us; speedup 1.0000x reference)
//
#include <hip/hip_runtime.h>
#include <hip/hip_bf16.h>

#define DEVI __device__ __forceinline__

typedef __attribute__((ext_vector_type(8))) __bf16 bf16x8;
typedef __attribute__((ext_vector_type(4))) float f32x4;
typedef __attribute__((ext_vector_type(4))) unsigned short u16x4;

DEVI unsigned short f2bf(float f) {
  unsigned int u = __float_as_uint(f);
  u += 0x7FFFu + ((u >> 16) & 1u);   // RNE
  return (unsigned short)(u >> 16);
}

#define GLD16(g, l) __builtin_amdgcn_global_load_lds(                      \
    (const __attribute__((address_space(1))) void*)(g),                    \
    (__attribute__((address_space(3))) void*)(l), 16, 0, 0)

// ---------------------------------------------------------------- helpers

__global__ __launch_bounds__(256) void cast_k(const float* __restrict__ in,
                                              unsigned short* __restrict__ out,
                                              int n4) {
  for (int i = blockIdx.x * 256 + threadIdx.x; i < n4; i += gridDim.x * 256) {
    f32x4 v = ((const f32x4*)in)[i];
    u16x4 o;
    o.x = f2bf(v.x); o.y = f2bf(v.y); o.z = f2bf(v.z); o.w = f2bf(v.w);
    ((u16x4*)out)[i] = o;
  }
}

// s[j] = g[j] / ||v[:,j]||  (column norms, 64 cols per block, 4 row-stripes)
__global__ __launch_bounds__(256) void colnorm_k(const float* __restrict__ v,
                                                 const float* __restrict__ g,
                                                 float* __restrict__ s,
                                                 int rows, int cols) {
  const int tid = threadIdx.x;
  const int c0 = blockIdx.x * 64;
  const int c = tid & 63, rg = tid >> 6;
  float acc = 0.f;
  for (int i = rg; i < rows; i += 4) {
    float x = v[(size_t)i * cols + c0 + c];
    acc += x * x;
  }
  __shared__ float red[256];
  red[tid] = acc;
  __syncthreads();
  if (tid < 64) {
    float t = red[tid] + red[tid + 64] + red[tid + 128] + red[tid + 192];
    s[c0 + tid] = g[c0 + tid] * rsqrtf(t);
  }
}

__global__ __launch_bounds__(256) void scale_cast_k(const float* __restrict__ in,
                                                    const float* __restrict__ s,
                                                    unsigned short* __restrict__ out,
                                                    int cols, int n4) {
  const int cmask4 = (cols >> 2) - 1;
  for (int i = blockIdx.x * 256 + threadIdx.x; i < n4; i += gridDim.x * 256) {
    f32x4 v = ((const f32x4*)in)[i];
    f32x4 sv = ((const f32x4*)s)[i & cmask4];
    u16x4 o;
    o.x = f2bf(v.x * sv.x); o.y = f2bf(v.y * sv.y);
    o.z = f2bf(v.z * sv.z); o.w = f2bf(v.w * sv.w);
    ((u16x4*)out)[i] = o;
  }
}

// LayerNorm: one block per row of 2048 fp32, out bf16
__global__ __launch_bounds__(256) void ln_k(const float* __restrict__ x,
                                            const float* __restrict__ g,
                                            const float* __restrict__ b,
                                            unsigned short* __restrict__ out) {
  const int tid = threadIdx.x, lane = tid & 63, wid = tid >> 6;
  const int row = blockIdx.x;
  const float* xr = x + (size_t)row * 2048;
  f32x4 a0 = ((const f32x4*)xr)[tid];
  f32x4 a1 = ((const f32x4*)xr)[tid + 256];
  float s = a0.x + a0.y + a0.z + a0.w + a1.x + a1.y + a1.z + a1.w;
  float ss = a0.x * a0.x + a0.y * a0.y + a0.z * a0.z + a0.w * a0.w +
             a1.x * a1.x + a1.y * a1.y + a1.z * a1.z + a1.w * a1.w;
#pragma unroll
  for (int m = 1; m < 64; m <<= 1) {
    s += __shfl_xor(s, m);
    ss += __shfl_xor(ss, m);
  }
  __shared__ float red[8];
  if (lane == 0) { red[wid] = s; red[4 + wid] = ss; }
  __syncthreads();
  s = red[0] + red[1] + red[2] + red[3];
  ss = red[4] + red[5] + red[6] + red[7];
  const float mu = s * (1.f / 2048.f);
  const float var = ss * (1.f / 2048.f) - mu * mu;
  const float rs = rsqrtf(var + 1e-5f);
  f32x4 g0 = ((const f32x4*)g)[tid], g1 = ((const f32x4*)g)[tid + 256];
  f32x4 b0 = ((const f32x4*)b)[tid], b1 = ((const f32x4*)b)[tid + 256];
  u16x4 o0, o1;
  o0.x = f2bf((a0.x - mu) * rs * g0.x + b0.x);
  o0.y = f2bf((a0.y - mu) * rs * g0.y + b0.y);
  o0.z = f2bf((a0.z - mu) * rs * g0.z + b0.z);
  o0.w = f2bf((a0.w - mu) * rs * g0.w + b0.w);
  o1.x = f2bf((a1.x - mu) * rs * g1.x + b1.x);
  o1.y = f2bf((a1.y - mu) * rs * g1.y + b1.y);
  o1.z = f2bf((a1.z - mu) * rs * g1.z + b1.z);
  o1.w = f2bf((a1.w - mu) * rs * g1.w + b1.w);
  unsigned short* orow = out + (size_t)row * 2048;
  *(u16x4*)(orow + 4 * tid) = o0;
  *(u16x4*)(orow + 1024 + 4 * tid) = o1;
}

// ---------------------------------------------------------------- GEMM
// C[m,n] = sum_k A[m,k]*B[n,k]  (B^T input), 128x128 tile, BK=32, 4 waves.
// EPI: 0 = +bias, scatter q/k/v^T   1 = +bias+res -> fp32
//      2 = +bias, GELU -> bf16      3 = same as 1
struct GemmP {
  const unsigned short* A;
  const unsigned short* B;
  const float* bias;
  const float* res;
  float* outF;
  unsigned short* outH;
  unsigned short* q;
  unsigned short* k;
  unsigned short* vt;
  int M, N, K;
};

template <int EPI>
__global__ __launch_bounds__(256) void gemm_bt(GemmP p) {
  const int tid = threadIdx.x, lane = tid & 63, wid = tid >> 6;
  const int nbm = p.M >> 7, nbn = p.N >> 7;
  const int nwg = nbm * nbn, qq = nwg >> 3;
  const int bid = blockIdx.x;
  const int wg = (bid & 7) * qq + (bid >> 3);      // XCD-bijective (nwg%8==0)
  const int bn = wg / nbm, bm = wg - bn * nbm;     // bn-major: share B-panel per XCD
  const int m0 = bm << 7, n0 = bn << 7;
  const int wr = wid >> 1, wc = wid & 1;
  const int K = p.K;

  __shared__ __align__(16) unsigned short sA[2][4096];
  __shared__ __align__(16) unsigned short sB[2][4096];

  const int c0 = tid, c1 = tid + 256;
  const unsigned short* gA0 = p.A + (size_t)(m0 + (c0 >> 2)) * K + ((c0 & 3) << 3);
  const unsigned short* gA1 = p.A + (size_t)(m0 + (c1 >> 2)) * K + ((c1 & 3) << 3);
  const unsigned short* gB0 = p.B + (size_t)(n0 + (c0 >> 2)) * K + ((c0 & 3) << 3);
  const unsigned short* gB1 = p.B + (size_t)(n0 + (c1 >> 2)) * K + ((c1 & 3) << 3);
  const int l0 = wid << 9, l1 = (wid << 9) + 2048;

  f32x4 acc[4][4] = {};
  const int arow = (wr << 6) + (lane & 15);
  const int brow = (wc << 6) + (lane & 15);
  const int koff = (lane >> 4) << 3;

#define STAGE(bufi, t) do { int ko = (t) << 5;          \
    GLD16(gA0 + ko, &sA[bufi][l0]);                     \
    GLD16(gA1 + ko, &sA[bufi][l1]);                     \
    GLD16(gB0 + ko, &sB[bufi][l0]);                     \
    GLD16(gB1 + ko, &sB[bufi][l1]); } while (0)

  STAGE(0, 0);
  __syncthreads();
  const int nk = K >> 5;
  int cur = 0;
  for (int t = 0; t < nk; ++t) {
    if (t + 1 < nk) STAGE(cur ^ 1, t + 1);
    bf16x8 af[4], bfr[4];
#pragma unroll
    for (int i = 0; i < 4; ++i)
      af[i] = *(const bf16x8*)&sA[cur][(arow + (i << 4)) * 32 + koff];
#pragma unroll
    for (int i = 0; i < 4; ++i)
      bfr[i] = *(const bf16x8*)&sB[cur][(brow + (i << 4)) * 32 + koff];
#pragma unroll
    for (int i = 0; i < 4; ++i)
#pragma unroll
      for (int j = 0; j < 4; ++j)
        acc[i][j] = __builtin_amdgcn_mfma_f32_16x16x32_bf16(af[i], bfr[j], acc[i][j], 0, 0, 0);
    __syncthreads();
    cur ^= 1;
  }
#undef STAGE

  const int rbase = m0 + (wr << 6) + ((lane >> 4) << 2);
  const int cbase = n0 + (wc << 6) + (lane & 15);
#pragma unroll
  for (int mi = 0; mi < 4; ++mi) {
#pragma unroll
    for (int ni = 0; ni < 4; ++ni) {
      const int col = cbase + (ni << 4);
      const float bb = p.bias[col];
#pragma unroll
      for (int r = 0; r < 4; ++r) {
        const int row = rbase + (mi << 4) + r;
        float v = acc[mi][ni][r] + bb;
        if constexpr (EPI == 0) {
          const int gsel = col >> 11, e = col & 2047;
          const int h = e >> 7, d = e & 127;
          const int bb2 = row >> 11, sidx = row & 2047;
          const size_t bh = (size_t)(bb2 * 16 + h);
          unsigned short hv = f2bf(v);
          if (gsel == 0)      p.q[(bh << 18) + ((size_t)sidx << 7) + d] = hv;
          else if (gsel == 1) p.k[(bh << 18) + ((size_t)sidx << 7) + d] = hv;
          else                p.vt[(bh << 18) + ((size_t)d << 11) + sidx] = hv;
        } else if constexpr (EPI == 1 || EPI == 3) {
          const size_t o = (size_t)row * p.N + col;
          p.outF[o] = v + p.res[o];
        } else {
          float gl = 0.5f * v * (1.0f + erff(v * 0.70710678118654752440f));
          p.outH[(size_t)row * p.N + col] = f2bf(gl);
        }
      }
    }
  }
}

// ---------------------------------------------------------------- attention
// Q,K in [B,H,S,D]; V^T in [B,H,D,S]; O (bf16) in [B,S,H*D]=[4096,2048].
// Block = 4 waves x 16 q-rows (QBLK=64), KVBLK=64, swapped QK^T (mfma(K,Q)):
// lane owns q = lane&15 (softmax state lane-local, 2 xor-shuffles to reduce).
__global__ __launch_bounds__(256) void attn_k(const unsigned short* __restrict__ Q,
                                              const unsigned short* __restrict__ Kg,
                                              const unsigned short* __restrict__ Vt,
                                              unsigned short* __restrict__ O) {
  const int tid = threadIdx.x, lane = tid & 63, wid = tid >> 6;
  const int bid = blockIdx.x;
  const int pos = bid >> 3;
  const int bh = (bid & 7) * 4 + (pos >> 5);  // 4 (b,h) groups per XCD: KV L2-resident
  const int qt = pos & 31;
  const int q0 = qt * 64 + wid * 16;
  const int b = bh >> 4, h = bh & 15;

  __shared__ __align__(16) unsigned short sK[64 * 128];  // XOR-swizzled rows
  __shared__ __align__(16) unsigned short sV[128 * 64];  // V^T, XOR-swizzled rows
  __shared__ __align__(16) unsigned short sP[4][16 * 72];

  const unsigned short* Qb = Q + ((size_t)bh << 18);
  const unsigned short* Kb = Kg + ((size_t)bh << 18);
  const unsigned short* Vb = Vt + ((size_t)bh << 18);

  bf16x8 qf[4];
  {
    const unsigned short* qp = Qb + (size_t)(q0 + (lane & 15)) * 128 + ((lane >> 4) << 3);
#pragma unroll
    for (int kk = 0; kk < 4; ++kk) qf[kk] = *(const bf16x8*)(qp + kk * 32);
  }

  f32x4 oacc[8] = {};
  float mrun = -3e38f, lrun = 0.f;

  for (int kt = 0; kt < 32; ++kt) {
    const int kv0 = kt << 6;
    // stage K [64][128] and V^T [128][64]; source pre-swizzled so that the
    // linear global_load_lds dest + swizzled ds_read form the same involution
#pragma unroll
    for (int i = 0; i < 4; ++i) {
      const int c = tid + (i << 8);
      const int ldsb = ((wid << 6) + (i << 8)) << 3;
      const int kv = c >> 4, jj = c & 15;
      const int js = (jj & 8) | ((jj ^ kv) & 7);
      GLD16(Kb + (size_t)(kv0 + kv) * 128 + (js << 3), &sK[ldsb]);
      const int d = c >> 3, j2 = c & 7;
      const int js2 = j2 ^ (d & 7);
      GLD16(Vb + (size_t)d * 2048 + kv0 + (js2 << 3), &sV[ldsb]);
    }
    __syncthreads();

    // S^T = K @ Q^T : D[kv][q], lane holds q=lane&15, 16 kv values
    f32x4 sc[4] = {};
#pragma unroll
    for (int ti = 0; ti < 4; ++ti) {
#pragma unroll
      for (int kk = 0; kk < 4; ++kk) {
        const int row = (ti << 4) + (lane & 15);
        int bo = (row << 8) + (kk << 6) + ((lane >> 4) << 4);
        bo ^= (row & 7) << 4;
        bf16x8 kf = *(const bf16x8*)((const char*)sK + bo);
        sc[ti] = __builtin_amdgcn_mfma_f32_16x16x32_bf16(kf, qf[kk], sc[ti], 0, 0, 0);
      }
    }

    // online softmax over this kv tile (emotion_bias dropped: softmax-invariant)
    float pv[16];
    float mx = -3e38f;
#pragma unroll
    for (int ti = 0; ti < 4; ++ti)
#pragma unroll
      for (int r = 0; r < 4; ++r) {
        float x = sc[ti][r] * 0.08838834764831845f;  // 1/sqrt(128)
        pv[(ti << 2) + r] = x;
        mx = fmaxf(mx, x);
      }
    mx = fmaxf(mx, __shfl_xor(mx, 16));
    mx = fmaxf(mx, __shfl_xor(mx, 32));
    const float mnew = fmaxf(mrun, mx);
    const float corr = __expf(mrun - mnew);
    float psum = 0.f;
#pragma unroll
    for (int i2 = 0; i2 < 16; ++i2) {
      float e = __expf(pv[i2] - mnew);
      pv[i2] = e;
      psum += e;
    }
    psum += __shfl_xor(psum, 16);
    psum += __shfl_xor(psum, 32);
    lrun = lrun * corr + psum;
    mrun = mnew;

    // write P (bf16) into per-wave LDS [16 q][72 kv-padded]
    unsigned short* prow = &sP[wid][(lane & 15) * 72];
#pragma unroll
    for (int ti = 0; ti < 4; ++ti) {
      u16x4 w4;
      w4.x = f2bf(pv[(ti << 2) + 0]);
      w4.y = f2bf(pv[(ti << 2) + 1]);
      w4.z = f2bf(pv[(ti << 2) + 2]);
      w4.w = f2bf(pv[(ti << 2) + 3]);
      *(u16x4*)&prow[(ti << 4) + ((lane >> 4) << 2)] = w4;
    }

    // rescale O accumulator (rows are q=(lane>>4)*4+r; state lives in lane q)
    float fr[4];
#pragma unroll
    for (int r = 0; r < 4; ++r) fr[r] = __shfl(corr, ((lane >> 4) << 2) + r);
#pragma unroll
    for (int di = 0; di < 8; ++di)
#pragma unroll
      for (int r = 0; r < 4; ++r) oacc[di][r] *= fr[r];

    // O += P @ V : A = P [q][kv], B = V^T [d][kv]
#pragma unroll
    for (int di = 0; di < 8; ++di) {
#pragma unroll
      for (int ks = 0; ks < 2; ++ks) {
        bf16x8 pf = *(const bf16x8*)((const char*)&sP[wid][0] +
                                     (lane & 15) * 144 + (ks << 6) + ((lane >> 4) << 4));
        const int dr = (di << 4) + (lane & 15);
        int bo = (dr << 7) + (ks << 6) + ((lane >> 4) << 4);
        bo ^= (dr & 7) << 4;
        bf16x8 vf = *(const bf16x8*)((const char*)sV + bo);
        oacc[di] = __builtin_amdgcn_mfma_f32_16x16x32_bf16(pf, vf, oacc[di], 0, 0, 0);
      }
    }
    __syncthreads();
  }

  float il[4];
#pragma unroll
  for (int r = 0; r < 4; ++r) il[r] = 1.f / __shfl(lrun, ((lane >> 4) << 2) + r);
  const size_t obase = ((size_t)(b * 2048 + q0)) * 2048 + h * 128;
#pragma unroll
  for (int di = 0; di < 8; ++di)
#pragma unroll
    for (int r = 0; r < 4; ++r) {
      const size_t o = obase + (size_t)(((lane >> 4) << 2) + r) * 2048 + (di << 4) + (lane & 15);
      O[o] = f2bf(oacc[di][r] * il[r]);
    }
}

// ---------------------------------------------------------------- launch

extern "C" void kernel_launch(void* const* d_in, const int* in_sizes, int n_in,
                              void* d_out, int out_size, void* d_ws, size_t ws_size,
                              hipStream_t stream) {
  (void)in_sizes; (void)n_in; (void)out_size; (void)ws_size;
  const float* hidden = (const float*)d_in[0];
  const float* ln1_g = (const float*)d_in[1];
  const float* ln1_b = (const float*)d_in[2];
  const float* w_qkv = (const float*)d_in[3];
  const float* b_qkv = (const float*)d_in[4];
  const float* apv = (const float*)d_in[5];
  const float* apg = (const float*)d_in[6];
  const float* apb = (const float*)d_in[7];
  // d_in[8] emotion_bias: constant per head over the softmax axis -> dropped (exact)
  const float* ln2_g = (const float*)d_in[9];
  const float* ln2_b = (const float*)d_in[10];
  const float* w_fc = (const float*)d_in[11];
  const float* b_fc = (const float*)d_in[12];
  const float* mpv = (const float*)d_in[13];
  const float* mpg = (const float*)d_in[14];
  const float* mpb = (const float*)d_in[15];

  char* w = (char*)d_ws;
  const size_t MBs = 1ull << 20;
  float* hidden2 = (float*)(w + 0);                          // 32 MiB
  unsigned short* hbuf = (unsigned short*)(w + 32 * MBs);    // 64 MiB
  unsigned short* qbuf = (unsigned short*)(w + 96 * MBs);    // 16 MiB
  unsigned short* kbuf = (unsigned short*)(w + 112 * MBs);   // 16 MiB
  unsigned short* vtbuf = (unsigned short*)(w + 128 * MBs);  // 16 MiB
  unsigned short* xln = (unsigned short*)(w + 144 * MBs);    // 16 MiB (xln -> attn_out)
  unsigned short* xln2 = (unsigned short*)(w + 160 * MBs);   // 16 MiB
  unsigned short* wqkv_bf = (unsigned short*)(w + 176 * MBs);  // 24 MiB
  unsigned short* wproj_bf = (unsigned short*)(w + 200 * MBs); // 8 MiB
  float* s_attn = (float*)(w + 208 * MBs);                   // 8 KiB
  float* s_mlp = (float*)(w + 208 * MBs + 32768);            // 32 KiB
  unsigned short* wfc_bf = qbuf;   // reuse q+k region after attention (32 MiB)
  unsigned short* w2_bf = vtbuf;   // reuse vt+attn_out region after GEMM2 (32 MiB)

  // weight prep
  cast_k<<<2048, 256, 0, stream>>>(w_qkv, wqkv_bf, (6144 * 2048) / 4);
  colnorm_k<<<32, 256, 0, stream>>>(apv, apg, s_attn, 2048, 2048);
  scale_cast_k<<<2048, 256, 0, stream>>>(apv, s_attn, wproj_bf, 2048, (2048 * 2048) / 4);
  colnorm_k<<<128, 256, 0, stream>>>(mpv, mpg, s_mlp, 2048, 8192);

  // LN1 -> xln (bf16)
  ln_k<<<4096, 256, 0, stream>>>(hidden, ln1_g, ln1_b, xln);

  // GEMM1: qkv = xln @ w_qkv^T + b, scattered to q/k [B,H,S,D], v^T [B,H,D,S]
  GemmP p1 = {xln, wqkv_bf, b_qkv, nullptr, nullptr, nullptr,
              qbuf, kbuf, vtbuf, 4096, 6144, 2048};
  gemm_bt<0><<<1536, 256, 0, stream>>>(p1);

  // attention -> attn_out (reuses xln slot)
  attn_k<<<1024, 256, 0, stream>>>(qbuf, kbuf, vtbuf, xln);

  // w_fc cast (into dead q/k region)
  cast_k<<<2048, 256, 0, stream>>>(w_fc, wfc_bf, (8192 * 2048) / 4);

  // GEMM2: hidden2 = attn_out @ w_proj^T + b + hidden
  GemmP p2 = {xln, wproj_bf, apb, hidden, hidden2, nullptr,
              nullptr, nullptr, nullptr, 4096, 2048, 2048};
  gemm_bt<1><<<512, 256, 0, stream>>>(p2);

  // w2 (weight-normed mlp proj) cast (into dead vt/attn_out region)
  scale_cast_k<<<4096, 256, 0, stream>>>(mpv, s_mlp, w2_bf, 8192, (2048 * 8192) / 4);

  // LN2 -> xln2
  ln_k<<<4096, 256, 0, stream>>>(hidden2, ln2_g, ln2_b, xln2);

  // GEMM3: h = gelu(xln2 @ w_fc^T + b_fc) (bf16)
  GemmP p3 = {xln2, wfc_bf, b_fc, nullptr, nullptr, hbuf,
              nullptr, nullptr, nullptr, 4096, 8192, 2048};
  gemm_bt<2><<<2048, 256, 0, stream>>>(p3);

  // GEMM4: out = h @ w2^T + b + hidden2 (fp32)
  GemmP p4 = {hbuf, w2_bf, mpb, hidden2, (float*)d_out, nullptr,
              nullptr, nullptr, nullptr, 4096, 2048, 8192};
  gemm_bt<3><<<512, 256, 0, stream>>>(p4);
}

// Round 2
// 1222.772 us; speedup vs baseline: 1.0517x; 1.0517x over previous
//
#include <hip/hip_runtime.h>
#include <hip/hip_bf16.h>

#define DEVI __device__ __forceinline__

typedef __attribute__((ext_vector_type(8))) __bf16 bf16x8;
typedef __attribute__((ext_vector_type(4))) float f32x4;
typedef __attribute__((ext_vector_type(4))) unsigned short u16x4;
typedef __attribute__((ext_vector_type(8))) unsigned short u16x8;

DEVI unsigned short f2bf(float f) {
  unsigned int u = __float_as_uint(f);
  u += 0x7FFFu + ((u >> 16) & 1u);   // RNE
  return (unsigned short)(u >> 16);
}

#define GLD16(g, l) __builtin_amdgcn_global_load_lds(                      \
    (const __attribute__((address_space(1))) void*)(g),                    \
    (__attribute__((address_space(3))) void*)(l), 16, 0, 0)

// ---------------------------------------------------------------- helpers

__global__ __launch_bounds__(256) void cast_k(const float* __restrict__ in,
                                              unsigned short* __restrict__ out,
                                              int n4) {
  for (int i = blockIdx.x * 256 + threadIdx.x; i < n4; i += gridDim.x * 256) {
    f32x4 v = ((const f32x4*)in)[i];
    u16x4 o;
    o.x = f2bf(v.x); o.y = f2bf(v.y); o.z = f2bf(v.z); o.w = f2bf(v.w);
    ((u16x4*)out)[i] = o;
  }
}

// s[j] = g[j] / ||v[:,j]||  (column norms, 64 cols per block, 4 row-stripes)
__global__ __launch_bounds__(256) void colnorm_k(const float* __restrict__ v,
                                                 const float* __restrict__ g,
                                                 float* __restrict__ s,
                                                 int rows, int cols) {
  const int tid = threadIdx.x;
  const int c0 = blockIdx.x * 64;
  const int c = tid & 63, rg = tid >> 6;
  float acc = 0.f;
  for (int i = rg; i < rows; i += 4) {
    float x = v[(size_t)i * cols + c0 + c];
    acc += x * x;
  }
  __shared__ float red[256];
  red[tid] = acc;
  __syncthreads();
  if (tid < 64) {
    float t = red[tid] + red[tid + 64] + red[tid + 128] + red[tid + 192];
    s[c0 + tid] = g[c0 + tid] * rsqrtf(t);
  }
}

__global__ __launch_bounds__(256) void scale_cast_k(const float* __restrict__ in,
                                                    const float* __restrict__ s,
                                                    unsigned short* __restrict__ out,
                                                    int cols, int n4) {
  const int cmask4 = (cols >> 2) - 1;
  for (int i = blockIdx.x * 256 + threadIdx.x; i < n4; i += gridDim.x * 256) {
    f32x4 v = ((const f32x4*)in)[i];
    f32x4 sv = ((const f32x4*)s)[i & cmask4];
    u16x4 o;
    o.x = f2bf(v.x * sv.x); o.y = f2bf(v.y * sv.y);
    o.z = f2bf(v.z * sv.z); o.w = f2bf(v.w * sv.w);
    ((u16x4*)out)[i] = o;
  }
}

// LayerNorm: one block per row of 2048 fp32, out bf16
__global__ __launch_bounds__(256) void ln_k(const float* __restrict__ x,
                                            const float* __restrict__ g,
                                            const float* __restrict__ b,
                                            unsigned short* __restrict__ out) {
  const int tid = threadIdx.x, lane = tid & 63, wid = tid >> 6;
  const int row = blockIdx.x;
  const float* xr = x + (size_t)row * 2048;
  f32x4 a0 = ((const f32x4*)xr)[tid];
  f32x4 a1 = ((const f32x4*)xr)[tid + 256];
  float s = a0.x + a0.y + a0.z + a0.w + a1.x + a1.y + a1.z + a1.w;
  float ss = a0.x * a0.x + a0.y * a0.y + a0.z * a0.z + a0.w * a0.w +
             a1.x * a1.x + a1.y * a1.y + a1.z * a1.z + a1.w * a1.w;
#pragma unroll
  for (int m = 1; m < 64; m <<= 1) {
    s += __shfl_xor(s, m);
    ss += __shfl_xor(ss, m);
  }
  __shared__ float red[8];
  if (lane == 0) { red[wid] = s; red[4 + wid] = ss; }
  __syncthreads();
  s = red[0] + red[1] + red[2] + red[3];
  ss = red[4] + red[5] + red[6] + red[7];
  const float mu = s * (1.f / 2048.f);
  const float var = ss * (1.f / 2048.f) - mu * mu;
  const float rs = rsqrtf(var + 1e-5f);
  f32x4 g0 = ((const f32x4*)g)[tid], g1 = ((const f32x4*)g)[tid + 256];
  f32x4 b0 = ((const f32x4*)b)[tid], b1 = ((const f32x4*)b)[tid + 256];
  u16x4 o0, o1;
  o0.x = f2bf((a0.x - mu) * rs * g0.x + b0.x);
  o0.y = f2bf((a0.y - mu) * rs * g0.y + b0.y);
  o0.z = f2bf((a0.z - mu) * rs * g0.z + b0.z);
  o0.w = f2bf((a0.w - mu) * rs * g0.w + b0.w);
  o1.x = f2bf((a1.x - mu) * rs * g1.x + b1.x);
  o1.y = f2bf((a1.y - mu) * rs * g1.y + b1.y);
  o1.z = f2bf((a1.z - mu) * rs * g1.z + b1.z);
  o1.w = f2bf((a1.w - mu) * rs * g1.w + b1.w);
  unsigned short* orow = out + (size_t)row * 2048;
  *(u16x4*)(orow + 4 * tid) = o0;
  *(u16x4*)(orow + 1024 + 4 * tid) = o1;
}

// V transpose: v [32][2048][128] -> vt [32][128][2048]
__global__ __launch_bounds__(256) void vtrans_k(const unsigned short* __restrict__ v,
                                                unsigned short* __restrict__ vt) {
  __shared__ unsigned short t[64][134];
  const int tid = threadIdx.x;
  const int bh = blockIdx.x >> 5, st = blockIdx.x & 31;
  const unsigned short* vb = v + ((size_t)bh << 18) + ((size_t)(st << 6) << 7);
#pragma unroll
  for (int i = 0; i < 4; ++i) {
    int f = tid + (i << 8);          // ushort8 id in [0,1024)
    int row = f >> 4, c8 = f & 15;
    u16x8 x = *(const u16x8*)(vb + row * 128 + c8 * 8);
#pragma unroll
    for (int j = 0; j < 4; ++j) {
      unsigned int pk = ((unsigned int)x[2 * j + 1] << 16) | x[2 * j];
      *(unsigned int*)&t[row][c8 * 8 + 2 * j] = pk;
    }
  }
  __syncthreads();
  const int lane = tid & 63, wid = tid >> 6;
  unsigned short* ob = vt + ((size_t)bh << 18) + (st << 6);
#pragma unroll
  for (int j = 0; j < 32; ++j) {
    int d = (wid << 5) + j;
    ob[((size_t)d << 11) + lane] = t[lane][d];
  }
}

// ---------------------------------------------------------------- GEMM params
struct GemmP {
  const unsigned short* A;
  const unsigned short* B;
  const float* bias;
  const float* res;
  float* outF;
  unsigned short* outH;
  unsigned short* q;
  unsigned short* k;
  unsigned short* vt;   // EPI0: v (row-major [B,H,S,D])
  int M, N, K;
};

// ---------------------------------------------------------------- 128^2 GEMM (2-phase)
// EPI: 1/3 = +bias+res -> fp32
template <int EPI>
__global__ __launch_bounds__(256) void gemm_bt(GemmP p) {
  const int tid = threadIdx.x, lane = tid & 63, wid = tid >> 6;
  const int nbm = p.M >> 7, nbn = p.N >> 7;
  const int nwg = nbm * nbn, qq = nwg >> 3;
  const int bid = blockIdx.x;
  const int wg = (bid & 7) * qq + (bid >> 3);      // XCD-bijective (nwg%8==0)
  const int bn = wg / nbm, bm = wg - bn * nbm;
  const int m0 = bm << 7, n0 = bn << 7;
  const int wr = wid >> 1, wc = wid & 1;
  const int K = p.K;

  __shared__ __align__(16) unsigned short sA[2][4096];
  __shared__ __align__(16) unsigned short sB[2][4096];

  const int c0 = tid, c1 = tid + 256;
  const unsigned short* gA0 = p.A + (size_t)(m0 + (c0 >> 2)) * K + ((c0 & 3) << 3);
  const unsigned short* gA1 = p.A + (size_t)(m0 + (c1 >> 2)) * K + ((c1 & 3) << 3);
  const unsigned short* gB0 = p.B + (size_t)(n0 + (c0 >> 2)) * K + ((c0 & 3) << 3);
  const unsigned short* gB1 = p.B + (size_t)(n0 + (c1 >> 2)) * K + ((c1 & 3) << 3);
  const int l0 = wid << 9, l1 = (wid << 9) + 2048;

  f32x4 acc[4][4] = {};
  const int arow = (wr << 6) + (lane & 15);
  const int brow = (wc << 6) + (lane & 15);
  const int koff = (lane >> 4) << 3;

#define STAGE(bufi, t) do { int ko = (t) << 5;          \
    GLD16(gA0 + ko, &sA[bufi][l0]);                     \
    GLD16(gA1 + ko, &sA[bufi][l1]);                     \
    GLD16(gB0 + ko, &sB[bufi][l0]);                     \
    GLD16(gB1 + ko, &sB[bufi][l1]); } while (0)

  STAGE(0, 0);
  __syncthreads();
  const int nk = K >> 5;
  int cur = 0;
  for (int t = 0; t < nk; ++t) {
    if (t + 1 < nk) STAGE(cur ^ 1, t + 1);
    bf16x8 af[4], bfr[4];
#pragma unroll
    for (int i = 0; i < 4; ++i)
      af[i] = *(const bf16x8*)&sA[cur][(arow + (i << 4)) * 32 + koff];
#pragma unroll
    for (int i = 0; i < 4; ++i)
      bfr[i] = *(const bf16x8*)&sB[cur][(brow + (i << 4)) * 32 + koff];
#pragma unroll
    for (int i = 0; i < 4; ++i)
#pragma unroll
      for (int j = 0; j < 4; ++j)
        acc[i][j] = __builtin_amdgcn_mfma_f32_16x16x32_bf16(af[i], bfr[j], acc[i][j], 0, 0, 0);
    __syncthreads();
    cur ^= 1;
  }
#undef STAGE

  const int rbase = m0 + (wr << 6) + ((lane >> 4) << 2);
  const int cbase = n0 + (wc << 6) + (lane & 15);
#pragma unroll
  for (int mi = 0; mi < 4; ++mi) {
#pragma unroll
    for (int ni = 0; ni < 4; ++ni) {
      const int col = cbase + (ni << 4);
      const float bb = p.bias[col];
#pragma unroll
      for (int r = 0; r < 4; ++r) {
        const int row = rbase + (mi << 4) + r;
        float v = acc[mi][ni][r] + bb;
        const size_t o = (size_t)row * p.N + col;
        p.outF[o] = v + p.res[o];
      }
    }
  }
}

// ---------------------------------------------------------------- 256^2 GEMM, 8-wave,
// BK=32, 4-buffer ring, counted vmcnt, st_16x32 swizzle (T2+T3+T4+T5).
// EPI: 0 = +bias, scatter q/k/v    2 = +bias, fast-GELU -> bf16
template <int EPI>
__global__ __launch_bounds__(512, 2) void gemm8p(GemmP p) {
  extern __shared__ unsigned short lds_raw[];   // [4 buf][A 8192 | B 8192] ushorts = 128 KiB
  const int tid = threadIdx.x, lane = tid & 63, wid = tid >> 6;
  const int nbm = p.M >> 8, nbn = p.N >> 8;
  const int nwg = nbm * nbn, cpx = nwg >> 3;
  const int bid = blockIdx.x;
  const int wg = (bid & 7) * cpx + (bid >> 3);   // XCD-bijective (nwg%8==0)
  const int bm = wg % nbm, bn = wg / nbm;        // consecutive wg share B-panel
  const int m0 = bm << 8, n0 = bn << 8;
  const int wr = wid >> 2, wc = wid & 3;         // 2x4 waves
  const int K = p.K;
  const int lr = lane & 15, lk = lane >> 4;
  // swizzled per-lane fragment byte offset within a 1024B subtile (st_16x32)
  const int fb = (lr * 64 + lk * 16) ^ ((lr & 8) << 2);

  // staging map: dest byte d (linear, global_load_lds) -> (r,c) source coords
  int r_[2], c_[2];
#pragma unroll
  for (int j = 0; j < 2; ++j) {
    int d = tid * 16 + j * 8192;
    int w = (d & 1023) ^ (((d >> 9) & 1) << 5);
    r_[j] = ((d >> 10) << 4) + (w >> 6);
    c_[j] = (w & 63) >> 1;
  }
  const unsigned short* gsA0 = p.A + (size_t)(m0 + r_[0]) * K + c_[0];
  const unsigned short* gsA1 = p.A + (size_t)(m0 + r_[1]) * K + c_[1];
  const unsigned short* gsB0 = p.B + (size_t)(n0 + r_[0]) * K + c_[0];
  const unsigned short* gsB1 = p.B + (size_t)(n0 + r_[1]) * K + c_[1];

#define STAGE_A8(b, kt) do { unsigned short* _d = lds_raw + ((b) << 14);       \
    GLD16(gsA0 + ((size_t)(kt) << 5), _d + (tid << 3));                        \
    GLD16(gsA1 + ((size_t)(kt) << 5), _d + 4096 + (tid << 3)); } while (0)
#define STAGE_B8(b, kt) do { unsigned short* _d = lds_raw + ((b) << 14) + 8192;\
    GLD16(gsB0 + ((size_t)(kt) << 5), _d + (tid << 3));                        \
    GLD16(gsB1 + ((size_t)(kt) << 5), _d + 4096 + (tid << 3)); } while (0)

  f32x4 acc[8][4] = {};
  const int NK = K >> 5;

  // prologue: kt0 -> buf0, kt1 -> buf1; wait for kt0 (4 newest may fly)
  STAGE_A8(0, 0); STAGE_B8(0, 0);
  STAGE_A8(1, 1); STAGE_B8(1, 1);
  asm volatile("s_waitcnt vmcnt(4)" ::: "memory");
  __builtin_amdgcn_s_barrier();
  __builtin_amdgcn_sched_barrier(0);

  for (int t = 0; t < NK; ++t) {
    const int bi = t & 3;
    const char* tA = (const char*)(lds_raw + (bi << 14));
    const char* tB = (const char*)(lds_raw + (bi << 14) + 8192);
    bf16x8 a_[4], b_[4];
    // ---- phase A: frags m0..3 (+ all B frags), stage A(t+2)
#pragma unroll
    for (int n = 0; n < 4; ++n)
      b_[n] = *(const bf16x8*)(tB + (((wc << 2) + n) << 10) + fb);
#pragma unroll
    for (int m = 0; m < 4; ++m)
      a_[m] = *(const bf16x8*)(tA + (((wr << 3) + m) << 10) + fb);
    if (t + 2 < NK) STAGE_A8((t + 2) & 3, t + 2);
    __builtin_amdgcn_s_barrier();
    __builtin_amdgcn_sched_barrier(0);
    __builtin_amdgcn_s_setprio(1);
#pragma unroll
    for (int m = 0; m < 4; ++m)
#pragma unroll
      for (int n = 0; n < 4; ++n)
        acc[m][n] = __builtin_amdgcn_mfma_f32_16x16x32_bf16(a_[m], b_[n], acc[m][n], 0, 0, 0);
    __builtin_amdgcn_s_setprio(0);
    __builtin_amdgcn_s_barrier();
    __builtin_amdgcn_sched_barrier(0);
    // ---- phase B: frags m4..7, stage B(t+2), counted vmcnt
#pragma unroll
    for (int m = 0; m < 4; ++m)
      a_[m] = *(const bf16x8*)(tA + (((wr << 3) + 4 + m) << 10) + fb);
    if (t + 2 < NK) STAGE_B8((t + 2) & 3, t + 2);
    if (t < NK - 2) asm volatile("s_waitcnt vmcnt(4)" ::: "memory");
    else            asm volatile("s_waitcnt vmcnt(0)" ::: "memory");
    __builtin_amdgcn_s_barrier();
    __builtin_amdgcn_sched_barrier(0);
    __builtin_amdgcn_s_setprio(1);
#pragma unroll
    for (int m = 0; m < 4; ++m)
#pragma unroll
      for (int n = 0; n < 4; ++n)
        acc[4 + m][n] = __builtin_amdgcn_mfma_f32_16x16x32_bf16(a_[m], b_[n], acc[4 + m][n], 0, 0, 0);
    __builtin_amdgcn_s_setprio(0);
    __builtin_amdgcn_s_barrier();
    __builtin_amdgcn_sched_barrier(0);
  }
#undef STAGE_A8
#undef STAGE_B8

  // epilogue
  const int rbase = m0 + wr * 128 + (lk << 2);
  const int cbase = n0 + wc * 64 + lr;
#pragma unroll
  for (int m = 0; m < 8; ++m) {
#pragma unroll
    for (int n = 0; n < 4; ++n) {
      const int col = cbase + (n << 4);
      const float bb = p.bias[col];
#pragma unroll
      for (int r = 0; r < 4; ++r) {
        const int row = rbase + (m << 4) + r;
        float v = acc[m][n][r] + bb;
        if constexpr (EPI == 0) {
          const int gsel = col >> 11, e = col & 2047;
          const int h = e >> 7, d = e & 127;
          const int b2 = row >> 11, sidx = row & 2047;
          const size_t off = ((size_t)(b2 * 16 + h) << 18) + ((size_t)sidx << 7) + d;
          unsigned short hv = f2bf(v);
          if (gsel == 0)      p.q[off] = hv;
          else if (gsel == 1) p.k[off] = hv;
          else                p.vt[off] = hv;   // v row-major; transposed later
        } else {
          float y = 0.7978845608028654f * (v + 0.044715f * v * v * v);
          float u = __expf(2.f * y);
          float gl = (y > 40.f) ? v : v * (u / (u + 1.f));
          p.outH[(size_t)row * p.N + col] = f2bf(gl);
        }
      }
    }
  }
}

// ---------------------------------------------------------------- attention
// Q,K in [B,H,S,D]; V^T in [B,H,D,S]; O (bf16) in [B,S,H*D]=[4096,2048].
__global__ __launch_bounds__(256) void attn_k(const unsigned short* __restrict__ Q,
                                              const unsigned short* __restrict__ Kg,
                                              const unsigned short* __restrict__ Vt,
                                              unsigned short* __restrict__ O) {
  const int tid = threadIdx.x, lane = tid & 63, wid = tid >> 6;
  const int bid = blockIdx.x;
  const int pos = bid >> 3;
  const int bh = (bid & 7) * 4 + (pos >> 5);
  const int qt = pos & 31;
  const int q0 = qt * 64 + wid * 16;
  const int b = bh >> 4, h = bh & 15;

  __shared__ __align__(16) unsigned short sK[64 * 128];
  __shared__ __align__(16) unsigned short sV[128 * 64];
  __shared__ __align__(16) unsigned short sP[4][16 * 72];

  const unsigned short* Qb = Q + ((size_t)bh << 18);
  const unsigned short* Kb = Kg + ((size_t)bh << 18);
  const unsigned short* Vb = Vt + ((size_t)bh << 18);

  bf16x8 qf[4];
  {
    const unsigned short* qp = Qb + (size_t)(q0 + (lane & 15)) * 128 + ((lane >> 4) << 3);
#pragma unroll
    for (int kk = 0; kk < 4; ++kk) qf[kk] = *(const bf16x8*)(qp + kk * 32);
  }

  f32x4 oacc[8] = {};
  float mrun = -3e38f, lrun = 0.f;

  for (int kt = 0; kt < 32; ++kt) {
    const int kv0 = kt << 6;
#pragma unroll
    for (int i = 0; i < 4; ++i) {
      const int c = tid + (i << 8);
      const int ldsb = ((wid << 6) + (i << 8)) << 3;
      const int kv = c >> 4, jj = c & 15;
      const int js = (jj & 8) | ((jj ^ kv) & 7);
      GLD16(Kb + (size_t)(kv0 + kv) * 128 + (js << 3), &sK[ldsb]);
      const int d = c >> 3, j2 = c & 7;
      const int js2 = j2 ^ (d & 7);
      GLD16(Vb + (size_t)d * 2048 + kv0 + (js2 << 3), &sV[ldsb]);
    }
    __syncthreads();

    f32x4 sc[4] = {};
#pragma unroll
    for (int ti = 0; ti < 4; ++ti) {
#pragma unroll
      for (int kk = 0; kk < 4; ++kk) {
        const int row = (ti << 4) + (lane & 15);
        int bo = (row << 8) + (kk << 6) + ((lane >> 4) << 4);
        bo ^= (row & 7) << 4;
        bf16x8 kf = *(const bf16x8*)((const char*)sK + bo);
        sc[ti] = __builtin_amdgcn_mfma_f32_16x16x32_bf16(kf, qf[kk], sc[ti], 0, 0, 0);
      }
    }

    float pv[16];
    float mx = -3e38f;
#pragma unroll
    for (int ti = 0; ti < 4; ++ti)
#pragma unroll
      for (int r = 0; r < 4; ++r) {
        float x = sc[ti][r] * 0.08838834764831845f;
        pv[(ti << 2) + r] = x;
        mx = fmaxf(mx, x);
      }
    mx = fmaxf(mx, __shfl_xor(mx, 16));
    mx = fmaxf(mx, __shfl_xor(mx, 32));
    const float mnew = fmaxf(mrun, mx);
    const float corr = __expf(mrun - mnew);
    float psum = 0.f;
#pragma unroll
    for (int i2 = 0; i2 < 16; ++i2) {
      float e = __expf(pv[i2] - mnew);
      pv[i2] = e;
      psum += e;
    }
    psum += __shfl_xor(psum, 16);
    psum += __shfl_xor(psum, 32);
    lrun = lrun * corr + psum;
    mrun = mnew;

    unsigned short* prow = &sP[wid][(lane & 15) * 72];
#pragma unroll
    for (int ti = 0; ti < 4; ++ti) {
      u16x4 w4;
      w4.x = f2bf(pv[(ti << 2) + 0]);
      w4.y = f2bf(pv[(ti << 2) + 1]);
      w4.z = f2bf(pv[(ti << 2) + 2]);
      w4.w = f2bf(pv[(ti << 2) + 3]);
      *(u16x4*)&prow[(ti << 4) + ((lane >> 4) << 2)] = w4;
    }

    float fr[4];
#pragma unroll
    for (int r = 0; r < 4; ++r) fr[r] = __shfl(corr, ((lane >> 4) << 2) + r);
#pragma unroll
    for (int di = 0; di < 8; ++di)
#pragma unroll
      for (int r = 0; r < 4; ++r) oacc[di][r] *= fr[r];

#pragma unroll
    for (int di = 0; di < 8; ++di) {
#pragma unroll
      for (int ks = 0; ks < 2; ++ks) {
        bf16x8 pf = *(const bf16x8*)((const char*)&sP[wid][0] +
                                     (lane & 15) * 144 + (ks << 6) + ((lane >> 4) << 4));
        const int dr = (di << 4) + (lane & 15);
        int bo = (dr << 7) + (ks << 6) + ((lane >> 4) << 4);
        bo ^= (dr & 7) << 4;
        bf16x8 vf = *(const bf16x8*)((const char*)sV + bo);
        oacc[di] = __builtin_amdgcn_mfma_f32_16x16x32_bf16(pf, vf, oacc[di], 0, 0, 0);
      }
    }
    __syncthreads();
  }

  float il[4];
#pragma unroll
  for (int r = 0; r < 4; ++r) il[r] = 1.f / __shfl(lrun, ((lane >> 4) << 2) + r);
  const size_t obase = ((size_t)(b * 2048 + q0)) * 2048 + h * 128;
#pragma unroll
  for (int di = 0; di < 8; ++di)
#pragma unroll
    for (int r = 0; r < 4; ++r) {
      const size_t o = obase + (size_t)(((lane >> 4) << 2) + r) * 2048 + (di << 4) + (lane & 15);
      O[o] = f2bf(oacc[di][r] * il[r]);
    }
}

// ---------------------------------------------------------------- launch

extern "C" void kernel_launch(void* const* d_in, const int* in_sizes, int n_in,
                              void* d_out, int out_size, void* d_ws, size_t ws_size,
                              hipStream_t stream) {
  (void)in_sizes; (void)n_in; (void)out_size; (void)ws_size;
  const float* hidden = (const float*)d_in[0];
  const float* ln1_g = (const float*)d_in[1];
  const float* ln1_b = (const float*)d_in[2];
  const float* w_qkv = (const float*)d_in[3];
  const float* b_qkv = (const float*)d_in[4];
  const float* apv = (const float*)d_in[5];
  const float* apg = (const float*)d_in[6];
  const float* apb = (const float*)d_in[7];
  // d_in[8] emotion_bias: softmax-invariant -> dropped (exact)
  const float* ln2_g = (const float*)d_in[9];
  const float* ln2_b = (const float*)d_in[10];
  const float* w_fc = (const float*)d_in[11];
  const float* b_fc = (const float*)d_in[12];
  const float* mpv = (const float*)d_in[13];
  const float* mpg = (const float*)d_in[14];
  const float* mpb = (const float*)d_in[15];

  char* w = (char*)d_ws;
  const size_t MBs = 1ull << 20;
  float* hidden2 = (float*)(w + 0);                           // 32 MiB (live G2..end)
  unsigned short* vbuf = (unsigned short*)(w + 32 * MBs);     // 16 MiB (G1..vtrans)
  unsigned short* vtbuf = (unsigned short*)(w + 48 * MBs);    // 16 MiB (vtrans..attn)
  unsigned short* hbuf = (unsigned short*)(w + 32 * MBs);     // 64 MiB (G3..G4, after attn)
  unsigned short* qbuf = (unsigned short*)(w + 96 * MBs);     // 16 MiB
  unsigned short* kbuf = (unsigned short*)(w + 112 * MBs);    // 16 MiB
  unsigned short* xln = (unsigned short*)(w + 128 * MBs);     // 16 MiB (xln -> attn_out)
  unsigned short* xln2 = (unsigned short*)(w + 144 * MBs);    // 16 MiB
  unsigned short* wqkv_bf = (unsigned short*)(w + 160 * MBs); // 24 MiB (dead after G1)
  unsigned short* w2_bf = (unsigned short*)(w + 160 * MBs);   // 32 MiB (after G1)
  unsigned short* wproj_bf = (unsigned short*)(w + 192 * MBs);// 8 MiB
  float* s_attn = (float*)(w + 200 * MBs);                    // 8 KiB
  float* s_mlp = (float*)(w + 200 * MBs + 32768);             // 32 KiB
  unsigned short* wfc_bf = qbuf;   // 32 MiB over dead q+k (after attn)

  hipFuncSetAttribute((const void*)gemm8p<0>, hipFuncAttributeMaxDynamicSharedMemorySize, 131072);
  hipFuncSetAttribute((const void*)gemm8p<2>, hipFuncAttributeMaxDynamicSharedMemorySize, 131072);

  // weight prep
  cast_k<<<2048, 256, 0, stream>>>(w_qkv, wqkv_bf, (6144 * 2048) / 4);
  colnorm_k<<<32, 256, 0, stream>>>(apv, apg, s_attn, 2048, 2048);
  scale_cast_k<<<2048, 256, 0, stream>>>(apv, s_attn, wproj_bf, 2048, (2048 * 2048) / 4);
  colnorm_k<<<128, 256, 0, stream>>>(mpv, mpg, s_mlp, 2048, 8192);

  // LN1 -> xln (bf16)
  ln_k<<<4096, 256, 0, stream>>>(hidden, ln1_g, ln1_b, xln);

  // GEMM1 (8-phase 256^2): qkv = xln @ w_qkv^T + b -> q/k/v [B,H,S,D]
  GemmP p1 = {xln, wqkv_bf, b_qkv, nullptr, nullptr, nullptr,
              qbuf, kbuf, vbuf, 4096, 6144, 2048};
  gemm8p<0><<<384, 512, 131072, stream>>>(p1);

  // V -> V^T
  vtrans_k<<<1024, 256, 0, stream>>>(vbuf, vtbuf);

  // attention -> attn_out (xln slot)
  attn_k<<<1024, 256, 0, stream>>>(qbuf, kbuf, vtbuf, xln);

  // weight casts for MLP (into regions dead after GEMM1/attn)
  cast_k<<<2048, 256, 0, stream>>>(w_fc, wfc_bf, (8192 * 2048) / 4);
  scale_cast_k<<<4096, 256, 0, stream>>>(mpv, s_mlp, w2_bf, 8192, (2048 * 8192) / 4);

  // GEMM2 (128^2): hidden2 = attn_out @ w_proj^T + b + hidden
  GemmP p2 = {xln, wproj_bf, apb, hidden, hidden2, nullptr,
              nullptr, nullptr, nullptr, 4096, 2048, 2048};
  gemm_bt<1><<<512, 256, 0, stream>>>(p2);

  // LN2 -> xln2
  ln_k<<<4096, 256, 0, stream>>>(hidden2, ln2_g, ln2_b, xln2);

  // GEMM3 (8-phase 256^2): h = gelu(xln2 @ w_fc^T + b_fc) (bf16)
  GemmP p3 = {xln2, wfc_bf, b_fc, nullptr, nullptr, hbuf,
              nullptr, nullptr, nullptr, 4096, 8192, 2048};
  gemm8p<2><<<512, 512, 131072, stream>>>(p3);

  // GEMM4 (128^2): out = h @ w2^T + b + hidden2 (fp32)
  GemmP p4 = {hbuf, w2_bf, mpb, hidden2, (float*)d_out, nullptr,
              nullptr, nullptr, nullptr, 4096, 2048, 8192};
  gemm_bt<3><<<512, 256, 0, stream>>>(p4);
}